// Round 8
// baseline (209.129 us; speedup 1.0000x reference)
//
#include <hip/hip_runtime.h>
#include <math.h>

// Problem constants
#define B_ 4
#define S_ 2048
#define E_ 512
#define H_ 8
#define D_ 64

typedef short bf16x8 __attribute__((ext_vector_type(8)));
typedef float f32x4 __attribute__((ext_vector_type(4)));

__device__ inline short f2bf(float f) {  // fp32 -> bf16 bits, RNE
  union { float f; unsigned u; } v; v.f = f;
  unsigned r = v.u + 0x7FFF + ((v.u >> 16) & 1);
  return (short)(r >> 16);
}
__device__ inline short f2bf_fast(float f) {  // round-half-up (P matrix only)
  union { float f; unsigned u; } v; v.f = f;
  return (short)((v.u + 0x8000u) >> 16);
}

// ---------------------------------------------------------------------------
// fp32 -> bf16 convert
// ---------------------------------------------------------------------------
__global__ __launch_bounds__(256) void cvt_bf16(const float* __restrict__ src,
                                                short* __restrict__ dst, int n4) {
  int i = blockIdx.x * 256 + threadIdx.x;
  if (i < n4) {
    float4 f = ((const float4*)src)[i];
    short4 o;
    o.x = f2bf(f.x); o.y = f2bf(f.y); o.z = f2bf(f.z); o.w = f2bf(f.w);
    ((short4*)dst)[i] = o;
  }
}

// ---------------------------------------------------------------------------
// MFMA GEMM 128x128 tile, BK=32, 4 waves (2x2). gemm_qkv: Y = Xb @ Winb^T;
// epilogue fuses RoPE; q,k stored [bh][s][d]; V stored TRANSPOSED [bh][d][s].
// ---------------------------------------------------------------------------
__global__ __launch_bounds__(256) void gemm_qkv_mfma(
    const short* __restrict__ Xb,    // [8192][512] bf16
    const short* __restrict__ Wb,    // [1536][512] bf16
    short* __restrict__ qb, short* __restrict__ kb, short* __restrict__ vbT) {
  __shared__ __align__(16) short As[128][40];
  __shared__ __align__(16) short Bs[128][40];
  const int tid = threadIdx.x;
  const int w = tid >> 6, lane = tid & 63;
  const int l15 = lane & 15, quad = lane >> 4;
  const int wm = w & 1, wn = w >> 1;
  const int m0 = blockIdx.x * 128;
  const int n0 = blockIdx.y * 128;
  f32x4 acc[4][4];
  for (int mt = 0; mt < 4; ++mt)
    for (int nt = 0; nt < 4; ++nt) acc[mt][nt] = (f32x4){0.f, 0.f, 0.f, 0.f};

  for (int k0 = 0; k0 < E_; k0 += 32) {
    __syncthreads();
    for (int l = 0; l < 2; ++l) {
      int c = tid + 256 * l;
      int row = c >> 2, k8 = (c & 3) * 8;
      *(bf16x8*)&As[row][k8] = *(const bf16x8*)&Xb[(size_t)(m0 + row) * E_ + k0 + k8];
      *(bf16x8*)&Bs[row][k8] = *(const bf16x8*)&Wb[(size_t)(n0 + row) * E_ + k0 + k8];
    }
    __syncthreads();
    bf16x8 a[4], bfr[4];
    for (int mt = 0; mt < 4; ++mt)
      a[mt] = *(const bf16x8*)&As[wm * 64 + mt * 16 + l15][quad * 8];
    for (int nt = 0; nt < 4; ++nt)
      bfr[nt] = *(const bf16x8*)&Bs[wn * 64 + nt * 16 + l15][quad * 8];
    for (int mt = 0; mt < 4; ++mt)
      for (int nt = 0; nt < 4; ++nt)
        acc[mt][nt] = __builtin_amdgcn_mfma_f32_16x16x32_bf16(a[mt], bfr[nt], acc[mt][nt], 0, 0, 0);
  }
  const int t3 = n0 >> 9;                  // uniform per block: 0=q 1=k 2=v
  for (int nt = 0; nt < 4; ++nt) {
    const int n = n0 + wn * 64 + nt * 16 + l15;
    const int h = (n >> 6) & 7;
    const int d = n & 63;
    const bool dorope = (t3 < 2) && (d < 32);
    const float sgn = (d & 1) ? 1.f : -1.f;
    const float fr = dorope ? powf(10000.f, -(float)(2 * (d >> 1)) * (1.f / 32.f)) : 0.f;
    for (int mt = 0; mt < 4; ++mt) {
      for (int i = 0; i < 4; ++i) {
        const int m = m0 + wm * 64 + mt * 16 + quad * 4 + i;
        const int b = m >> 11, s = m & (S_ - 1);
        float val = acc[mt][nt][i];
        float pv = __shfl_xor(val, 1, 64);
        float outv = val;
        if (dorope) {
          float ang = (float)s * fr;
          float sn, cs;
          sincosf(ang, &sn, &cs);
          outv = val * cs + pv * sgn * sn;
        }
        if (t3 == 2)
          vbT[((size_t)(b * 8 + h) * D_ + d) * S_ + s] = f2bf(outv);
        else {
          short* dst = (t3 == 0) ? qb : kb;
          dst[(((size_t)(b * 8 + h)) * S_ + s) * D_ + d] = f2bf(outv);
        }
      }
    }
  }
}

// ---------------------------------------------------------------------------
// gemm_out: out = ob @ Woutb^T, fp32 output
// ---------------------------------------------------------------------------
__global__ __launch_bounds__(256) void gemm_out_mfma(
    const short* __restrict__ Ab, const short* __restrict__ Wb,
    float* __restrict__ out) {
  __shared__ __align__(16) short As[128][40];
  __shared__ __align__(16) short Bs[128][40];
  const int tid = threadIdx.x;
  const int w = tid >> 6, lane = tid & 63;
  const int l15 = lane & 15, quad = lane >> 4;
  const int wm = w & 1, wn = w >> 1;
  const int m0 = blockIdx.x * 128;
  const int n0 = blockIdx.y * 128;
  f32x4 acc[4][4];
  for (int mt = 0; mt < 4; ++mt)
    for (int nt = 0; nt < 4; ++nt) acc[mt][nt] = (f32x4){0.f, 0.f, 0.f, 0.f};

  for (int k0 = 0; k0 < E_; k0 += 32) {
    __syncthreads();
    for (int l = 0; l < 2; ++l) {
      int c = tid + 256 * l;
      int row = c >> 2, k8 = (c & 3) * 8;
      *(bf16x8*)&As[row][k8] = *(const bf16x8*)&Ab[(size_t)(m0 + row) * E_ + k0 + k8];
      *(bf16x8*)&Bs[row][k8] = *(const bf16x8*)&Wb[(size_t)(n0 + row) * E_ + k0 + k8];
    }
    __syncthreads();
    bf16x8 a[4], bfr[4];
    for (int mt = 0; mt < 4; ++mt)
      a[mt] = *(const bf16x8*)&As[wm * 64 + mt * 16 + l15][quad * 8];
    for (int nt = 0; nt < 4; ++nt)
      bfr[nt] = *(const bf16x8*)&Bs[wn * 64 + nt * 16 + l15][quad * 8];
    for (int mt = 0; mt < 4; ++mt)
      for (int nt = 0; nt < 4; ++nt)
        acc[mt][nt] = __builtin_amdgcn_mfma_f32_16x16x32_bf16(a[mt], bfr[nt], acc[mt][nt], 0, 0, 0);
  }
  for (int mt = 0; mt < 4; ++mt)
    for (int nt = 0; nt < 4; ++nt) {
      const int n = n0 + wn * 64 + nt * 16 + l15;
      for (int i = 0; i < 4; ++i) {
        const int m = m0 + wm * 64 + mt * 16 + quad * 4 + i;
        out[(size_t)m * E_ + n] = acc[mt][nt][i];
      }
    }
}

// ---------------------------------------------------------------------------
// Flash attention, MFMA, static-max softmax. BR=64, BC=64. Grid (32,32):
// one q-tile per block (4 blocks/CU vs 2 before). CU-balance swizzle under
// the round-robin dispatch model: flipping qt on (bh>>3)&1 pairs qt with
// 31-qt per CU -> every CU gets ~66 k-tiles. Perf heuristic only.
// Softmax: p = exp2(fma(s, c2, bias[col])); bias folds scale/shift/colmask.
// Causal cndmask only on the boundary tile.
// ---------------------------------------------------------------------------
__global__ __launch_bounds__(256) void flash_mfma(
    const short* __restrict__ qb, const short* __restrict__ kb,
    const short* __restrict__ vbT, const int* __restrict__ maskp,
    short* __restrict__ ob) {
  __shared__ __align__(16) short Ks[64][72];
  __shared__ __align__(16) short VT[64][72];
  __shared__ __align__(16) short Pl[4][16][72];
  __shared__ float kbias[64];
  const int tid = threadIdx.x;
  const int w = tid >> 6, lane = tid & 63;
  const int l15 = lane & 15, quad = lane >> 4;
  const int bh = blockIdx.y, b = bh >> 3, h = bh & 7;
  int qtb = (blockIdx.x + ((bh & 7) << 2)) & 31;
  const int qt = ((bh >> 3) & 1) ? 31 - qtb : qtb;
  const int r0 = qt * 64;
  const short* qbase = qb + (size_t)bh * S_ * D_;
  const short* kbase = kb + (size_t)bh * S_ * D_;
  const short* vtb   = vbT + (size_t)bh * D_ * S_;
  const float c2 = 0.1803368801f;          // 0.125 * log2(e)
  bf16x8 ones;
  for (int j = 0; j < 8; ++j) ones[j] = (short)0x3F80;  // bf16 1.0

  bf16x8 aq[2];
  {
    const short* qrow = qbase + (size_t)(r0 + 16 * w + l15) * D_;
    aq[0] = *(const bf16x8*)&qrow[quad * 8];
    aq[1] = *(const bf16x8*)&qrow[32 + quad * 8];
  }
  f32x4 o[4], lsum;
  for (int no = 0; no < 4; ++no) o[no] = (f32x4){0.f, 0.f, 0.f, 0.f};
  lsum = (f32x4){0.f, 0.f, 0.f, 0.f};

  for (int kt = 0; kt <= qt; ++kt) {
    const int t0 = kt * 64;
    __syncthreads();
    for (int l = 0; l < 2; ++l) {
      int idx = tid + 256 * l;
      int row = idx >> 3, ch = (idx & 7) * 8;
      *(bf16x8*)&Ks[row][ch] = *(const bf16x8*)(kbase + (size_t)(t0 + row) * D_ + ch);
      *(bf16x8*)&VT[row][ch] = *(const bf16x8*)(vtb + (size_t)row * S_ + t0 + ch);
    }
    if (tid < 64)
      kbias[tid] = maskp[b * S_ + t0 + tid] ? -23.08312f : -1.0e38f;
    __syncthreads();
    f32x4 sfr[4];
    for (int nb = 0; nb < 4; ++nb) sfr[nb] = (f32x4){0.f, 0.f, 0.f, 0.f};
    for (int nb = 0; nb < 4; ++nb)
      for (int ks = 0; ks < 2; ++ks) {
        bf16x8 bk = *(const bf16x8*)&Ks[l15 + 16 * nb][32 * ks + quad * 8];
        sfr[nb] = __builtin_amdgcn_mfma_f32_16x16x32_bf16(aq[ks], bk, sfr[nb], 0, 0, 0);
      }
    if (kt < qt) {                          // interior: no causal test
      for (int nb = 0; nb < 4; ++nb) {
        const float bb = kbias[l15 + 16 * nb];
        for (int i = 0; i < 4; ++i)
          Pl[w][quad * 4 + i][l15 + 16 * nb] = f2bf_fast(exp2f(sfr[nb][i] * c2 + bb));
      }
    } else {                                // boundary tile: add causal mask
      for (int nb = 0; nb < 4; ++nb) {
        const int tg = l15 + 16 * nb;
        const float bb = kbias[l15 + 16 * nb];
        for (int i = 0; i < 4; ++i) {
          const float bbi = (tg > 16 * w + quad * 4 + i) ? -1.0e38f : bb;
          Pl[w][quad * 4 + i][l15 + 16 * nb] = f2bf_fast(exp2f(sfr[nb][i] * c2 + bbi));
        }
      }
    }
    asm volatile("s_waitcnt lgkmcnt(0)" ::: "memory");  // own-wave Pl writes
    bf16x8 ap0 = *(const bf16x8*)&Pl[w][l15][quad * 8];
    bf16x8 ap1 = *(const bf16x8*)&Pl[w][l15][32 + quad * 8];
    for (int no = 0; no < 4; ++no) {
      bf16x8 bv0 = *(const bf16x8*)&VT[16 * no + l15][quad * 8];
      bf16x8 bv1 = *(const bf16x8*)&VT[16 * no + l15][32 + quad * 8];
      o[no] = __builtin_amdgcn_mfma_f32_16x16x32_bf16(ap0, bv0, o[no], 0, 0, 0);
      o[no] = __builtin_amdgcn_mfma_f32_16x16x32_bf16(ap1, bv1, o[no], 0, 0, 0);
    }
    lsum = __builtin_amdgcn_mfma_f32_16x16x32_bf16(ap0, ones, lsum, 0, 0, 0);
    lsum = __builtin_amdgcn_mfma_f32_16x16x32_bf16(ap1, ones, lsum, 0, 0, 0);
  }
  // epilogue: rows with mask=0 output V[s] exactly; else normalize
  for (int i = 0; i < 4; ++i) {
    const int s = r0 + 16 * w + quad * 4 + i;
    const int qm = maskp[b * S_ + s];
    const float inv = 1.f / lsum[i];
    short* orow = ob + ((size_t)(b * S_ + s)) * E_ + h * D_;
    for (int no = 0; no < 4; ++no) {
      const int d = l15 + 16 * no;
      orow[d] = qm ? f2bf(o[no][i] * inv) : vtb[(size_t)d * S_ + s];
    }
  }
}

extern "C" void kernel_launch(void* const* d_in, const int* in_sizes, int n_in,
                              void* d_out, int out_size, void* d_ws, size_t ws_size,
                              hipStream_t stream) {
  const float* x    = (const float*)d_in[0];
  const int*   mask = (const int*)d_in[1];
  const float* Win  = (const float*)d_in[2];
  const float* Wout = (const float*)d_in[3];
  float* out = (float*)d_out;

  short* Xb    = (short*)d_ws;               // 8192*512
  short* Winb  = Xb + 8192 * 512;            // 1536*512
  short* Woutb = Winb + 1536 * 512;          // 512*512
  short* qb    = Woutb + 512 * 512;          // 32*2048*64 each
  short* kb    = qb + 32 * 2048 * 64;
  short* vbT   = kb + 32 * 2048 * 64;        // [bh][d][s] transposed
  short* ob    = vbT + 32 * 2048 * 64;       // 8192*512

  cvt_bf16<<<4096, 256, 0, stream>>>(x, Xb, 8192 * 512 / 4);
  cvt_bf16<<<768, 256, 0, stream>>>(Win, Winb, 1536 * 512 / 4);
  cvt_bf16<<<256, 256, 0, stream>>>(Wout, Woutb, 512 * 512 / 4);
  gemm_qkv_mfma<<<dim3(64, 12), 256, 0, stream>>>(Xb, Winb, qb, kb, vbT);
  flash_mfma<<<dim3(32, 32), 256, 0, stream>>>(qb, kb, vbT, mask, ob);
  gemm_out_mfma<<<dim3(64, 4), 256, 0, stream>>>(ob, Woutb, out);
}

// Round 9
// 191.099 us; speedup vs baseline: 1.0943x; 1.0943x over previous
//
#include <hip/hip_runtime.h>
#include <math.h>

// Problem constants
#define B_ 4
#define S_ 2048
#define E_ 512
#define H_ 8
#define D_ 64

typedef short bf16x8 __attribute__((ext_vector_type(8)));
typedef float f32x4 __attribute__((ext_vector_type(4)));

__device__ inline short f2bf(float f) {  // fp32 -> bf16 bits, RNE
  union { float f; unsigned u; } v; v.f = f;
  unsigned r = v.u + 0x7FFF + ((v.u >> 16) & 1);
  return (short)(r >> 16);
}
__device__ inline short f2bf_fast(float f) {  // round-half-up (P matrix only)
  union { float f; unsigned u; } v; v.f = f;
  return (short)((v.u + 0x8000u) >> 16);
}

// ---------------------------------------------------------------------------
// fp32 -> bf16 convert
// ---------------------------------------------------------------------------
__global__ __launch_bounds__(256) void cvt_bf16(const float* __restrict__ src,
                                                short* __restrict__ dst, int n4) {
  int i = blockIdx.x * 256 + threadIdx.x;
  if (i < n4) {
    float4 f = ((const float4*)src)[i];
    short4 o;
    o.x = f2bf(f.x); o.y = f2bf(f.y); o.z = f2bf(f.z); o.w = f2bf(f.w);
    ((short4*)dst)[i] = o;
  }
}

// ---------------------------------------------------------------------------
// MFMA GEMM 128x128 tile, BK=32, 4 waves (2x2). gemm_qkv: Y = Xb @ Winb^T;
// epilogue fuses RoPE; q,k stored [bh][s][d]; V stored TRANSPOSED [bh][d][s].
// ---------------------------------------------------------------------------
__global__ __launch_bounds__(256) void gemm_qkv_mfma(
    const short* __restrict__ Xb,    // [8192][512] bf16
    const short* __restrict__ Wb,    // [1536][512] bf16
    short* __restrict__ qb, short* __restrict__ kb, short* __restrict__ vbT) {
  __shared__ __align__(16) short As[128][40];
  __shared__ __align__(16) short Bs[128][40];
  const int tid = threadIdx.x;
  const int w = tid >> 6, lane = tid & 63;
  const int l15 = lane & 15, quad = lane >> 4;
  const int wm = w & 1, wn = w >> 1;
  const int m0 = blockIdx.x * 128;
  const int n0 = blockIdx.y * 128;
  f32x4 acc[4][4];
  for (int mt = 0; mt < 4; ++mt)
    for (int nt = 0; nt < 4; ++nt) acc[mt][nt] = (f32x4){0.f, 0.f, 0.f, 0.f};

  for (int k0 = 0; k0 < E_; k0 += 32) {
    __syncthreads();
    for (int l = 0; l < 2; ++l) {
      int c = tid + 256 * l;
      int row = c >> 2, k8 = (c & 3) * 8;
      *(bf16x8*)&As[row][k8] = *(const bf16x8*)&Xb[(size_t)(m0 + row) * E_ + k0 + k8];
      *(bf16x8*)&Bs[row][k8] = *(const bf16x8*)&Wb[(size_t)(n0 + row) * E_ + k0 + k8];
    }
    __syncthreads();
    bf16x8 a[4], bfr[4];
    for (int mt = 0; mt < 4; ++mt)
      a[mt] = *(const bf16x8*)&As[wm * 64 + mt * 16 + l15][quad * 8];
    for (int nt = 0; nt < 4; ++nt)
      bfr[nt] = *(const bf16x8*)&Bs[wn * 64 + nt * 16 + l15][quad * 8];
    for (int mt = 0; mt < 4; ++mt)
      for (int nt = 0; nt < 4; ++nt)
        acc[mt][nt] = __builtin_amdgcn_mfma_f32_16x16x32_bf16(a[mt], bfr[nt], acc[mt][nt], 0, 0, 0);
  }
  const int t3 = n0 >> 9;                  // uniform per block: 0=q 1=k 2=v
  for (int nt = 0; nt < 4; ++nt) {
    const int n = n0 + wn * 64 + nt * 16 + l15;
    const int h = (n >> 6) & 7;
    const int d = n & 63;
    const bool dorope = (t3 < 2) && (d < 32);
    const float sgn = (d & 1) ? 1.f : -1.f;
    const float fr = dorope ? powf(10000.f, -(float)(2 * (d >> 1)) * (1.f / 32.f)) : 0.f;
    for (int mt = 0; mt < 4; ++mt) {
      for (int i = 0; i < 4; ++i) {
        const int m = m0 + wm * 64 + mt * 16 + quad * 4 + i;
        const int b = m >> 11, s = m & (S_ - 1);
        float val = acc[mt][nt][i];
        float pv = __shfl_xor(val, 1, 64);
        float outv = val;
        if (dorope) {
          float ang = (float)s * fr;
          float sn, cs;
          sincosf(ang, &sn, &cs);
          outv = val * cs + pv * sgn * sn;
        }
        if (t3 == 2)
          vbT[((size_t)(b * 8 + h) * D_ + d) * S_ + s] = f2bf(outv);
        else {
          short* dst = (t3 == 0) ? qb : kb;
          dst[(((size_t)(b * 8 + h)) * S_ + s) * D_ + d] = f2bf(outv);
        }
      }
    }
  }
}

// ---------------------------------------------------------------------------
// gemm_out: out = ob @ Woutb^T, fp32 output
// ---------------------------------------------------------------------------
__global__ __launch_bounds__(256) void gemm_out_mfma(
    const short* __restrict__ Ab, const short* __restrict__ Wb,
    float* __restrict__ out) {
  __shared__ __align__(16) short As[128][40];
  __shared__ __align__(16) short Bs[128][40];
  const int tid = threadIdx.x;
  const int w = tid >> 6, lane = tid & 63;
  const int l15 = lane & 15, quad = lane >> 4;
  const int wm = w & 1, wn = w >> 1;
  const int m0 = blockIdx.x * 128;
  const int n0 = blockIdx.y * 128;
  f32x4 acc[4][4];
  for (int mt = 0; mt < 4; ++mt)
    for (int nt = 0; nt < 4; ++nt) acc[mt][nt] = (f32x4){0.f, 0.f, 0.f, 0.f};

  for (int k0 = 0; k0 < E_; k0 += 32) {
    __syncthreads();
    for (int l = 0; l < 2; ++l) {
      int c = tid + 256 * l;
      int row = c >> 2, k8 = (c & 3) * 8;
      *(bf16x8*)&As[row][k8] = *(const bf16x8*)&Ab[(size_t)(m0 + row) * E_ + k0 + k8];
      *(bf16x8*)&Bs[row][k8] = *(const bf16x8*)&Wb[(size_t)(n0 + row) * E_ + k0 + k8];
    }
    __syncthreads();
    bf16x8 a[4], bfr[4];
    for (int mt = 0; mt < 4; ++mt)
      a[mt] = *(const bf16x8*)&As[wm * 64 + mt * 16 + l15][quad * 8];
    for (int nt = 0; nt < 4; ++nt)
      bfr[nt] = *(const bf16x8*)&Bs[wn * 64 + nt * 16 + l15][quad * 8];
    for (int mt = 0; mt < 4; ++mt)
      for (int nt = 0; nt < 4; ++nt)
        acc[mt][nt] = __builtin_amdgcn_mfma_f32_16x16x32_bf16(a[mt], bfr[nt], acc[mt][nt], 0, 0, 0);
  }
  for (int mt = 0; mt < 4; ++mt)
    for (int nt = 0; nt < 4; ++nt) {
      const int n = n0 + wn * 64 + nt * 16 + l15;
      for (int i = 0; i < 4; ++i) {
        const int m = m0 + wm * 64 + mt * 16 + quad * 4 + i;
        out[(size_t)m * E_ + n] = acc[mt][nt][i];
      }
    }
}

// ---------------------------------------------------------------------------
// Flash attention, MFMA, static-max softmax. BR=64, BC=64.
// Round-7 structure: grid 512 (flat), every block = one (bh, pair) with the
// complementary q-tiles (qt, 31-qt) -> exactly 33 k-tile stagings per block
// (uniform; balance independent of dispatch mapping).
// XCD-locality swizzle: under the id&7 -> XCD round-robin model, map
// bid -> u=bid&7, v=bid>>3, bh=(u<<2)|(v&3), pair=v>>2. Then each XCD hosts
// only 4 bh -> K/V working set 2 MB fits its 4 MB L2 (was 32 bh = 16 MB,
// thrash -> 124 MB HBM refetch). Heuristic only; any mapping stays correct
// and balanced.
// Softmax: p = exp2(fma(s, c2, bias[col])); bias folds scale/shift/colmask;
// causal test only on the boundary tile.
// ---------------------------------------------------------------------------
__global__ __launch_bounds__(256) void flash_mfma(
    const short* __restrict__ qb, const short* __restrict__ kb,
    const short* __restrict__ vbT, const int* __restrict__ maskp,
    short* __restrict__ ob) {
  __shared__ __align__(16) short Ks[64][72];
  __shared__ __align__(16) short VT[64][72];
  __shared__ __align__(16) short Pl[4][16][72];
  __shared__ float kbias[64];
  const int tid = threadIdx.x;
  const int w = tid >> 6, lane = tid & 63;
  const int l15 = lane & 15, quad = lane >> 4;
  const int bid = blockIdx.x;
  const int u = bid & 7, v = bid >> 3;
  const int bh = (u << 2) | (v & 3);       // 4 bh per XCD under id&7 model
  const int pair = v >> 2;                 // 0..15
  const int b = bh >> 3, h = bh & 7;
  const short* qbase = qb + (size_t)bh * S_ * D_;
  const short* kbase = kb + (size_t)bh * S_ * D_;
  const short* vtb   = vbT + (size_t)bh * D_ * S_;
  const float c2 = 0.1803368801f;          // 0.125 * log2(e)
  bf16x8 ones;
  for (int j = 0; j < 8; ++j) ones[j] = (short)0x3F80;  // bf16 1.0

  for (int seg = 0; seg < 2; ++seg) {
    const int qt = (seg == 0) ? pair : 31 - pair;
    const int r0 = qt * 64;
    bf16x8 aq[2];
    {
      const short* qrow = qbase + (size_t)(r0 + 16 * w + l15) * D_;
      aq[0] = *(const bf16x8*)&qrow[quad * 8];
      aq[1] = *(const bf16x8*)&qrow[32 + quad * 8];
    }
    f32x4 o[4], lsum;
    for (int no = 0; no < 4; ++no) o[no] = (f32x4){0.f, 0.f, 0.f, 0.f};
    lsum = (f32x4){0.f, 0.f, 0.f, 0.f};

    for (int kt = 0; kt <= qt; ++kt) {
      const int t0 = kt * 64;
      __syncthreads();                     // prior tile fully consumed
      for (int l = 0; l < 2; ++l) {
        int idx = tid + 256 * l;
        int row = idx >> 3, ch = (idx & 7) * 8;
        *(bf16x8*)&Ks[row][ch] = *(const bf16x8*)(kbase + (size_t)(t0 + row) * D_ + ch);
        *(bf16x8*)&VT[row][ch] = *(const bf16x8*)(vtb + (size_t)row * S_ + t0 + ch);
      }
      if (tid < 64)
        kbias[tid] = maskp[b * S_ + t0 + tid] ? -23.08312f : -1.0e38f;
      __syncthreads();
      f32x4 sfr[4];
      for (int nb = 0; nb < 4; ++nb) sfr[nb] = (f32x4){0.f, 0.f, 0.f, 0.f};
      for (int nb = 0; nb < 4; ++nb)
        for (int ks = 0; ks < 2; ++ks) {
          bf16x8 bk = *(const bf16x8*)&Ks[l15 + 16 * nb][32 * ks + quad * 8];
          sfr[nb] = __builtin_amdgcn_mfma_f32_16x16x32_bf16(aq[ks], bk, sfr[nb], 0, 0, 0);
        }
      if (kt < qt) {                       // interior tiles: no causal test
        for (int nb = 0; nb < 4; ++nb) {
          const float bb = kbias[l15 + 16 * nb];
          for (int i = 0; i < 4; ++i)
            Pl[w][quad * 4 + i][l15 + 16 * nb] = f2bf_fast(exp2f(sfr[nb][i] * c2 + bb));
        }
      } else {                             // boundary tile: add causal mask
        for (int nb = 0; nb < 4; ++nb) {
          const int tg = l15 + 16 * nb;
          const float bb = kbias[l15 + 16 * nb];
          for (int i = 0; i < 4; ++i) {
            const float bbi = (tg > 16 * w + quad * 4 + i) ? -1.0e38f : bb;
            Pl[w][quad * 4 + i][l15 + 16 * nb] = f2bf_fast(exp2f(sfr[nb][i] * c2 + bbi));
          }
        }
      }
      asm volatile("s_waitcnt lgkmcnt(0)" ::: "memory");  // own-wave Pl writes
      bf16x8 ap0 = *(const bf16x8*)&Pl[w][l15][quad * 8];
      bf16x8 ap1 = *(const bf16x8*)&Pl[w][l15][32 + quad * 8];
      for (int no = 0; no < 4; ++no) {
        bf16x8 bv0 = *(const bf16x8*)&VT[16 * no + l15][quad * 8];
        bf16x8 bv1 = *(const bf16x8*)&VT[16 * no + l15][32 + quad * 8];
        o[no] = __builtin_amdgcn_mfma_f32_16x16x32_bf16(ap0, bv0, o[no], 0, 0, 0);
        o[no] = __builtin_amdgcn_mfma_f32_16x16x32_bf16(ap1, bv1, o[no], 0, 0, 0);
      }
      lsum = __builtin_amdgcn_mfma_f32_16x16x32_bf16(ap0, ones, lsum, 0, 0, 0);
      lsum = __builtin_amdgcn_mfma_f32_16x16x32_bf16(ap1, ones, lsum, 0, 0, 0);
    }
    // epilogue: rows with mask=0 output V[s] exactly; else normalize
    for (int i = 0; i < 4; ++i) {
      const int s = r0 + 16 * w + quad * 4 + i;
      const int qm = maskp[b * S_ + s];
      const float inv = 1.f / lsum[i];
      short* orow = ob + ((size_t)(b * S_ + s)) * E_ + h * D_;
      for (int no = 0; no < 4; ++no) {
        const int d = l15 + 16 * no;
        orow[d] = qm ? f2bf(o[no][i] * inv) : vtb[(size_t)d * S_ + s];
      }
    }
  }
}

extern "C" void kernel_launch(void* const* d_in, const int* in_sizes, int n_in,
                              void* d_out, int out_size, void* d_ws, size_t ws_size,
                              hipStream_t stream) {
  const float* x    = (const float*)d_in[0];
  const int*   mask = (const int*)d_in[1];
  const float* Win  = (const float*)d_in[2];
  const float* Wout = (const float*)d_in[3];
  float* out = (float*)d_out;

  short* Xb    = (short*)d_ws;               // 8192*512
  short* Winb  = Xb + 8192 * 512;            // 1536*512
  short* Woutb = Winb + 1536 * 512;          // 512*512
  short* qb    = Woutb + 512 * 512;          // 32*2048*64 each
  short* kb    = qb + 32 * 2048 * 64;
  short* vbT   = kb + 32 * 2048 * 64;        // [bh][d][s] transposed
  short* ob    = vbT + 32 * 2048 * 64;       // 8192*512

  cvt_bf16<<<4096, 256, 0, stream>>>(x, Xb, 8192 * 512 / 4);
  cvt_bf16<<<768, 256, 0, stream>>>(Win, Winb, 1536 * 512 / 4);
  cvt_bf16<<<256, 256, 0, stream>>>(Wout, Woutb, 512 * 512 / 4);
  gemm_qkv_mfma<<<dim3(64, 12), 256, 0, stream>>>(Xb, Winb, qb, kb, vbT);
  flash_mfma<<<512, 256, 0, stream>>>(qb, kb, vbT, mask, ob);
  gemm_out_mfma<<<dim3(64, 4), 256, 0, stream>>>(ob, Woutb, out);
}

// Round 10
// 187.574 us; speedup vs baseline: 1.1149x; 1.0188x over previous
//
#include <hip/hip_runtime.h>
#include <math.h>

// Problem constants
#define B_ 4
#define S_ 2048
#define E_ 512
#define H_ 8
#define D_ 64

typedef short bf16x8 __attribute__((ext_vector_type(8)));
typedef float f32x4 __attribute__((ext_vector_type(4)));

__device__ inline short f2bf(float f) {  // fp32 -> bf16 bits, RNE
  union { float f; unsigned u; } v; v.f = f;
  unsigned r = v.u + 0x7FFF + ((v.u >> 16) & 1);
  return (short)(r >> 16);
}
__device__ inline short f2bf_fast(float f) {  // round-half-up (P matrix only)
  union { float f; unsigned u; } v; v.f = f;
  return (short)((v.u + 0x8000u) >> 16);
}

// ---------------------------------------------------------------------------
// fp32 -> bf16 convert
// ---------------------------------------------------------------------------
__global__ __launch_bounds__(256) void cvt_bf16(const float* __restrict__ src,
                                                short* __restrict__ dst, int n4) {
  int i = blockIdx.x * 256 + threadIdx.x;
  if (i < n4) {
    float4 f = ((const float4*)src)[i];
    short4 o;
    o.x = f2bf(f.x); o.y = f2bf(f.y); o.z = f2bf(f.z); o.w = f2bf(f.w);
    ((short4*)dst)[i] = o;
  }
}

// ---------------------------------------------------------------------------
// MFMA GEMM 128x128 tile, BK=32, 4 waves (2x2). gemm_qkv: Y = Xb @ Winb^T;
// epilogue fuses RoPE; q,k stored [bh][s][d]; V stored TRANSPOSED [bh][d][s].
// (unchanged this round — isolate the flash dbuf change)
// ---------------------------------------------------------------------------
__global__ __launch_bounds__(256) void gemm_qkv_mfma(
    const short* __restrict__ Xb,    // [8192][512] bf16
    const short* __restrict__ Wb,    // [1536][512] bf16
    short* __restrict__ qb, short* __restrict__ kb, short* __restrict__ vbT) {
  __shared__ __align__(16) short As[128][40];
  __shared__ __align__(16) short Bs[128][40];
  const int tid = threadIdx.x;
  const int w = tid >> 6, lane = tid & 63;
  const int l15 = lane & 15, quad = lane >> 4;
  const int wm = w & 1, wn = w >> 1;
  const int m0 = blockIdx.x * 128;
  const int n0 = blockIdx.y * 128;
  f32x4 acc[4][4];
  for (int mt = 0; mt < 4; ++mt)
    for (int nt = 0; nt < 4; ++nt) acc[mt][nt] = (f32x4){0.f, 0.f, 0.f, 0.f};

  for (int k0 = 0; k0 < E_; k0 += 32) {
    __syncthreads();
    for (int l = 0; l < 2; ++l) {
      int c = tid + 256 * l;
      int row = c >> 2, k8 = (c & 3) * 8;
      *(bf16x8*)&As[row][k8] = *(const bf16x8*)&Xb[(size_t)(m0 + row) * E_ + k0 + k8];
      *(bf16x8*)&Bs[row][k8] = *(const bf16x8*)&Wb[(size_t)(n0 + row) * E_ + k0 + k8];
    }
    __syncthreads();
    bf16x8 a[4], bfr[4];
    for (int mt = 0; mt < 4; ++mt)
      a[mt] = *(const bf16x8*)&As[wm * 64 + mt * 16 + l15][quad * 8];
    for (int nt = 0; nt < 4; ++nt)
      bfr[nt] = *(const bf16x8*)&Bs[wn * 64 + nt * 16 + l15][quad * 8];
    for (int mt = 0; mt < 4; ++mt)
      for (int nt = 0; nt < 4; ++nt)
        acc[mt][nt] = __builtin_amdgcn_mfma_f32_16x16x32_bf16(a[mt], bfr[nt], acc[mt][nt], 0, 0, 0);
  }
  const int t3 = n0 >> 9;                  // uniform per block: 0=q 1=k 2=v
  for (int nt = 0; nt < 4; ++nt) {
    const int n = n0 + wn * 64 + nt * 16 + l15;
    const int h = (n >> 6) & 7;
    const int d = n & 63;
    const bool dorope = (t3 < 2) && (d < 32);
    const float sgn = (d & 1) ? 1.f : -1.f;
    const float fr = dorope ? powf(10000.f, -(float)(2 * (d >> 1)) * (1.f / 32.f)) : 0.f;
    for (int mt = 0; mt < 4; ++mt) {
      for (int i = 0; i < 4; ++i) {
        const int m = m0 + wm * 64 + mt * 16 + quad * 4 + i;
        const int b = m >> 11, s = m & (S_ - 1);
        float val = acc[mt][nt][i];
        float pv = __shfl_xor(val, 1, 64);
        float outv = val;
        if (dorope) {
          float ang = (float)s * fr;
          float sn, cs;
          sincosf(ang, &sn, &cs);
          outv = val * cs + pv * sgn * sn;
        }
        if (t3 == 2)
          vbT[((size_t)(b * 8 + h) * D_ + d) * S_ + s] = f2bf(outv);
        else {
          short* dst = (t3 == 0) ? qb : kb;
          dst[(((size_t)(b * 8 + h)) * S_ + s) * D_ + d] = f2bf(outv);
        }
      }
    }
  }
}

// ---------------------------------------------------------------------------
// gemm_out: out = ob @ Woutb^T, fp32 output (unchanged this round)
// ---------------------------------------------------------------------------
__global__ __launch_bounds__(256) void gemm_out_mfma(
    const short* __restrict__ Ab, const short* __restrict__ Wb,
    float* __restrict__ out) {
  __shared__ __align__(16) short As[128][40];
  __shared__ __align__(16) short Bs[128][40];
  const int tid = threadIdx.x;
  const int w = tid >> 6, lane = tid & 63;
  const int l15 = lane & 15, quad = lane >> 4;
  const int wm = w & 1, wn = w >> 1;
  const int m0 = blockIdx.x * 128;
  const int n0 = blockIdx.y * 128;
  f32x4 acc[4][4];
  for (int mt = 0; mt < 4; ++mt)
    for (int nt = 0; nt < 4; ++nt) acc[mt][nt] = (f32x4){0.f, 0.f, 0.f, 0.f};

  for (int k0 = 0; k0 < E_; k0 += 32) {
    __syncthreads();
    for (int l = 0; l < 2; ++l) {
      int c = tid + 256 * l;
      int row = c >> 2, k8 = (c & 3) * 8;
      *(bf16x8*)&As[row][k8] = *(const bf16x8*)&Ab[(size_t)(m0 + row) * E_ + k0 + k8];
      *(bf16x8*)&Bs[row][k8] = *(const bf16x8*)&Wb[(size_t)(n0 + row) * E_ + k0 + k8];
    }
    __syncthreads();
    bf16x8 a[4], bfr[4];
    for (int mt = 0; mt < 4; ++mt)
      a[mt] = *(const bf16x8*)&As[wm * 64 + mt * 16 + l15][quad * 8];
    for (int nt = 0; nt < 4; ++nt)
      bfr[nt] = *(const bf16x8*)&Bs[wn * 64 + nt * 16 + l15][quad * 8];
    for (int mt = 0; mt < 4; ++mt)
      for (int nt = 0; nt < 4; ++nt)
        acc[mt][nt] = __builtin_amdgcn_mfma_f32_16x16x32_bf16(a[mt], bfr[nt], acc[mt][nt], 0, 0, 0);
  }
  for (int mt = 0; mt < 4; ++mt)
    for (int nt = 0; nt < 4; ++nt) {
      const int n = n0 + wn * 64 + nt * 16 + l15;
      for (int i = 0; i < 4; ++i) {
        const int m = m0 + wm * 64 + mt * 16 + quad * 4 + i;
        out[(size_t)m * E_ + n] = acc[mt][nt][i];
      }
    }
}

// ---------------------------------------------------------------------------
// Flash attention, MFMA, static-max softmax. BR=64, BC=64, grid 512 flat,
// XCD swizzle (verified round 9: FETCH 124->12.4 MB), balanced (qt, 31-qt)
// pairs. NEW: double-buffered K/V staging, ONE barrier per tile:
//   loop kt: issue global loads for kt+1 (regs, async)
//            compute tile kt from buf[kt&1]
//            write staged regs to buf[(kt+1)&1]
//            __syncthreads()
// Load latency overlaps the current tile's MFMA+softmax; the barrier's
// vmcnt drain is cheap because loads were issued a full tile earlier.
// ---------------------------------------------------------------------------
__global__ __launch_bounds__(256) void flash_mfma(
    const short* __restrict__ qb, const short* __restrict__ kb,
    const short* __restrict__ vbT, const int* __restrict__ maskp,
    short* __restrict__ ob) {
  __shared__ __align__(16) short Ks[2][64][72];
  __shared__ __align__(16) short VT[2][64][72];
  __shared__ __align__(16) short Pl[4][16][72];
  __shared__ float kbias[2][64];
  const int tid = threadIdx.x;
  const int w = tid >> 6, lane = tid & 63;
  const int l15 = lane & 15, quad = lane >> 4;
  const int bid = blockIdx.x;
  const int u = bid & 7, v = bid >> 3;
  const int bh = (u << 2) | (v & 3);       // 4 bh per XCD under id&7 model
  const int pair = v >> 2;                 // 0..15
  const int b = bh >> 3, h = bh & 7;
  const short* qbase = qb + (size_t)bh * S_ * D_;
  const short* kbase = kb + (size_t)bh * S_ * D_;
  const short* vtb   = vbT + (size_t)bh * D_ * S_;
  const float c2 = 0.1803368801f;          // 0.125 * log2(e)
  const int srow = tid >> 3, sch = (tid & 7) * 8;   // staging coords
  bf16x8 ones;
  for (int j = 0; j < 8; ++j) ones[j] = (short)0x3F80;  // bf16 1.0

  for (int seg = 0; seg < 2; ++seg) {
    const int qt = (seg == 0) ? pair : 31 - pair;
    const int r0 = qt * 64;
    bf16x8 aq[2];
    {
      const short* qrow = qbase + (size_t)(r0 + 16 * w + l15) * D_;
      aq[0] = *(const bf16x8*)&qrow[quad * 8];
      aq[1] = *(const bf16x8*)&qrow[32 + quad * 8];
    }
    f32x4 o[4], lsum;
    for (int no = 0; no < 4; ++no) o[no] = (f32x4){0.f, 0.f, 0.f, 0.f};
    lsum = (f32x4){0.f, 0.f, 0.f, 0.f};

    // prologue: stage tile 0 into buf 0
    {
      bf16x8 kv0 = *(const bf16x8*)(kbase + (size_t)srow * D_ + sch);
      bf16x8 kv1 = *(const bf16x8*)(kbase + (size_t)(32 + srow) * D_ + sch);
      bf16x8 vv0 = *(const bf16x8*)(vtb + (size_t)srow * S_ + sch);
      bf16x8 vv1 = *(const bf16x8*)(vtb + (size_t)(32 + srow) * S_ + sch);
      int km = (tid < 64) ? maskp[b * S_ + tid] : 0;
      __syncthreads();                      // prior segment fully consumed
      *(bf16x8*)&Ks[0][srow][sch] = kv0;
      *(bf16x8*)&Ks[0][32 + srow][sch] = kv1;
      *(bf16x8*)&VT[0][srow][sch] = vv0;
      *(bf16x8*)&VT[0][32 + srow][sch] = vv1;
      if (tid < 64) kbias[0][tid] = km ? -23.08312f : -1.0e38f;
      __syncthreads();
    }

    for (int kt = 0; kt <= qt; ++kt) {
      const int cur = kt & 1;
      // issue next tile's loads (async; consumed after compute)
      bf16x8 kv0, kv1, vv0, vv1; int km = 0;
      if (kt < qt) {
        const int t1 = (kt + 1) * 64;
        kv0 = *(const bf16x8*)(kbase + (size_t)(t1 + srow) * D_ + sch);
        kv1 = *(const bf16x8*)(kbase + (size_t)(t1 + 32 + srow) * D_ + sch);
        vv0 = *(const bf16x8*)(vtb + (size_t)srow * S_ + t1 + sch);
        vv1 = *(const bf16x8*)(vtb + (size_t)(32 + srow) * S_ + t1 + sch);
        km = (tid < 64) ? maskp[b * S_ + t1 + tid] : 0;
      }
      // compute tile kt from buf[cur]
      f32x4 sfr[4];
      for (int nb = 0; nb < 4; ++nb) sfr[nb] = (f32x4){0.f, 0.f, 0.f, 0.f};
      for (int nb = 0; nb < 4; ++nb)
        for (int ks = 0; ks < 2; ++ks) {
          bf16x8 bk = *(const bf16x8*)&Ks[cur][l15 + 16 * nb][32 * ks + quad * 8];
          sfr[nb] = __builtin_amdgcn_mfma_f32_16x16x32_bf16(aq[ks], bk, sfr[nb], 0, 0, 0);
        }
      if (kt < qt) {                       // interior tiles: no causal test
        for (int nb = 0; nb < 4; ++nb) {
          const float bb = kbias[cur][l15 + 16 * nb];
          for (int i = 0; i < 4; ++i)
            Pl[w][quad * 4 + i][l15 + 16 * nb] = f2bf_fast(exp2f(sfr[nb][i] * c2 + bb));
        }
      } else {                             // boundary tile: add causal mask
        for (int nb = 0; nb < 4; ++nb) {
          const int tg = l15 + 16 * nb;
          const float bb = kbias[cur][l15 + 16 * nb];
          for (int i = 0; i < 4; ++i) {
            const float bbi = (tg > 16 * w + quad * 4 + i) ? -1.0e38f : bb;
            Pl[w][quad * 4 + i][l15 + 16 * nb] = f2bf_fast(exp2f(sfr[nb][i] * c2 + bbi));
          }
        }
      }
      asm volatile("s_waitcnt lgkmcnt(0)" ::: "memory");  // own-wave Pl writes
      bf16x8 ap0 = *(const bf16x8*)&Pl[w][l15][quad * 8];
      bf16x8 ap1 = *(const bf16x8*)&Pl[w][l15][32 + quad * 8];
      for (int no = 0; no < 4; ++no) {
        bf16x8 bv0 = *(const bf16x8*)&VT[cur][16 * no + l15][quad * 8];
        bf16x8 bv1 = *(const bf16x8*)&VT[cur][16 * no + l15][32 + quad * 8];
        o[no] = __builtin_amdgcn_mfma_f32_16x16x32_bf16(ap0, bv0, o[no], 0, 0, 0);
        o[no] = __builtin_amdgcn_mfma_f32_16x16x32_bf16(ap1, bv1, o[no], 0, 0, 0);
      }
      lsum = __builtin_amdgcn_mfma_f32_16x16x32_bf16(ap0, ones, lsum, 0, 0, 0);
      lsum = __builtin_amdgcn_mfma_f32_16x16x32_bf16(ap1, ones, lsum, 0, 0, 0);
      // write next tile into the other buffer (safe: its readers finished
      // at the barrier ending iteration kt-1)
      if (kt < qt) {
        const int nxt = cur ^ 1;
        *(bf16x8*)&Ks[nxt][srow][sch] = kv0;
        *(bf16x8*)&Ks[nxt][32 + srow][sch] = kv1;
        *(bf16x8*)&VT[nxt][srow][sch] = vv0;
        *(bf16x8*)&VT[nxt][32 + srow][sch] = vv1;
        if (tid < 64) kbias[nxt][tid] = km ? -23.08312f : -1.0e38f;
      }
      __syncthreads();
    }
    // epilogue: rows with mask=0 output V[s] exactly; else normalize
    for (int i = 0; i < 4; ++i) {
      const int s = r0 + 16 * w + quad * 4 + i;
      const int qm = maskp[b * S_ + s];
      const float inv = 1.f / lsum[i];
      short* orow = ob + ((size_t)(b * S_ + s)) * E_ + h * D_;
      for (int no = 0; no < 4; ++no) {
        const int d = l15 + 16 * no;
        orow[d] = qm ? f2bf(o[no][i] * inv) : vtb[(size_t)d * S_ + s];
      }
    }
  }
}

extern "C" void kernel_launch(void* const* d_in, const int* in_sizes, int n_in,
                              void* d_out, int out_size, void* d_ws, size_t ws_size,
                              hipStream_t stream) {
  const float* x    = (const float*)d_in[0];
  const int*   mask = (const int*)d_in[1];
  const float* Win  = (const float*)d_in[2];
  const float* Wout = (const float*)d_in[3];
  float* out = (float*)d_out;

  short* Xb    = (short*)d_ws;               // 8192*512
  short* Winb  = Xb + 8192 * 512;            // 1536*512
  short* Woutb = Winb + 1536 * 512;          // 512*512
  short* qb    = Woutb + 512 * 512;          // 32*2048*64 each
  short* kb    = qb + 32 * 2048 * 64;
  short* vbT   = kb + 32 * 2048 * 64;        // [bh][d][s] transposed
  short* ob    = vbT + 32 * 2048 * 64;       // 8192*512

  cvt_bf16<<<4096, 256, 0, stream>>>(x, Xb, 8192 * 512 / 4);
  cvt_bf16<<<768, 256, 0, stream>>>(Win, Winb, 1536 * 512 / 4);
  cvt_bf16<<<256, 256, 0, stream>>>(Wout, Woutb, 512 * 512 / 4);
  gemm_qkv_mfma<<<dim3(64, 12), 256, 0, stream>>>(Xb, Winb, qb, kb, vbT);
  flash_mfma<<<512, 256, 0, stream>>>(qb, kb, vbT, mask, ob);
  gemm_out_mfma<<<dim3(64, 4), 256, 0, stream>>>(ob, Woutb, out);
}

// Round 11
// 178.304 us; speedup vs baseline: 1.1729x; 1.0520x over previous
//
#include <hip/hip_runtime.h>
#include <math.h>

// Problem constants
#define B_ 4
#define S_ 2048
#define E_ 512
#define H_ 8
#define D_ 64

typedef short bf16x8 __attribute__((ext_vector_type(8)));
typedef float f32x4 __attribute__((ext_vector_type(4)));

__device__ inline short f2bf(float f) {  // fp32 -> bf16 bits, RNE
  union { float f; unsigned u; } v; v.f = f;
  unsigned r = v.u + 0x7FFF + ((v.u >> 16) & 1);
  return (short)(r >> 16);
}
__device__ inline short f2bf_fast(float f) {  // round-half-up (P matrix only)
  union { float f; unsigned u; } v; v.f = f;
  return (short)((v.u + 0x8000u) >> 16);
}
__device__ inline float bf2f(short s) {
  union { unsigned u; float f; } v; v.u = ((unsigned)(unsigned short)s) << 16;
  return v.f;
}

// ---------------------------------------------------------------------------
// fp32 -> bf16 convert
// ---------------------------------------------------------------------------
__global__ __launch_bounds__(256) void cvt_bf16(const float* __restrict__ src,
                                                short* __restrict__ dst, int n4) {
  int i = blockIdx.x * 256 + threadIdx.x;
  if (i < n4) {
    float4 f = ((const float4*)src)[i];
    short4 o;
    o.x = f2bf(f.x); o.y = f2bf(f.y); o.z = f2bf(f.z); o.w = f2bf(f.w);
    ((short4*)dst)[i] = o;
  }
}

// ---------------------------------------------------------------------------
// MFMA GEMM 128x128 tile, BK=32, 4 waves (2x2). gemm_qkv: Y = Xb @ Winb^T;
// epilogue fuses RoPE; q,k stored [bh][s][d]; V stored TRANSPOSED [bh][d][s].
// ---------------------------------------------------------------------------
__global__ __launch_bounds__(256) void gemm_qkv_mfma(
    const short* __restrict__ Xb,    // [8192][512] bf16
    const short* __restrict__ Wb,    // [1536][512] bf16
    short* __restrict__ qb, short* __restrict__ kb, short* __restrict__ vbT) {
  __shared__ __align__(16) short As[128][40];
  __shared__ __align__(16) short Bs[128][40];
  const int tid = threadIdx.x;
  const int w = tid >> 6, lane = tid & 63;
  const int l15 = lane & 15, quad = lane >> 4;
  const int wm = w & 1, wn = w >> 1;
  const int m0 = blockIdx.x * 128;
  const int n0 = blockIdx.y * 128;
  f32x4 acc[4][4];
  for (int mt = 0; mt < 4; ++mt)
    for (int nt = 0; nt < 4; ++nt) acc[mt][nt] = (f32x4){0.f, 0.f, 0.f, 0.f};

  for (int k0 = 0; k0 < E_; k0 += 32) {
    __syncthreads();
    for (int l = 0; l < 2; ++l) {
      int c = tid + 256 * l;
      int row = c >> 2, k8 = (c & 3) * 8;
      *(bf16x8*)&As[row][k8] = *(const bf16x8*)&Xb[(size_t)(m0 + row) * E_ + k0 + k8];
      *(bf16x8*)&Bs[row][k8] = *(const bf16x8*)&Wb[(size_t)(n0 + row) * E_ + k0 + k8];
    }
    __syncthreads();
    bf16x8 a[4], bfr[4];
    for (int mt = 0; mt < 4; ++mt)
      a[mt] = *(const bf16x8*)&As[wm * 64 + mt * 16 + l15][quad * 8];
    for (int nt = 0; nt < 4; ++nt)
      bfr[nt] = *(const bf16x8*)&Bs[wn * 64 + nt * 16 + l15][quad * 8];
    for (int mt = 0; mt < 4; ++mt)
      for (int nt = 0; nt < 4; ++nt)
        acc[mt][nt] = __builtin_amdgcn_mfma_f32_16x16x32_bf16(a[mt], bfr[nt], acc[mt][nt], 0, 0, 0);
  }
  const int t3 = n0 >> 9;                  // uniform per block: 0=q 1=k 2=v
  for (int nt = 0; nt < 4; ++nt) {
    const int n = n0 + wn * 64 + nt * 16 + l15;
    const int h = (n >> 6) & 7;
    const int d = n & 63;
    const bool dorope = (t3 < 2) && (d < 32);
    const float sgn = (d & 1) ? 1.f : -1.f;
    const float fr = dorope ? powf(10000.f, -(float)(2 * (d >> 1)) * (1.f / 32.f)) : 0.f;
    for (int mt = 0; mt < 4; ++mt) {
      for (int i = 0; i < 4; ++i) {
        const int m = m0 + wm * 64 + mt * 16 + quad * 4 + i;
        const int b = m >> 11, s = m & (S_ - 1);
        float val = acc[mt][nt][i];
        float pv = __shfl_xor(val, 1, 64);
        float outv = val;
        if (dorope) {
          float ang = (float)s * fr;
          float sn, cs;
          sincosf(ang, &sn, &cs);
          outv = val * cs + pv * sgn * sn;
        }
        if (t3 == 2)
          vbT[((size_t)(b * 8 + h) * D_ + d) * S_ + s] = f2bf(outv);
        else {
          short* dst = (t3 == 0) ? qb : kb;
          dst[(((size_t)(b * 8 + h)) * S_ + s) * D_ + d] = f2bf(outv);
        }
      }
    }
  }
}

// ---------------------------------------------------------------------------
// gemm_out: out = ob @ Woutb^T, fp32 output
// ---------------------------------------------------------------------------
__global__ __launch_bounds__(256) void gemm_out_mfma(
    const short* __restrict__ Ab, const short* __restrict__ Wb,
    float* __restrict__ out) {
  __shared__ __align__(16) short As[128][40];
  __shared__ __align__(16) short Bs[128][40];
  const int tid = threadIdx.x;
  const int w = tid >> 6, lane = tid & 63;
  const int l15 = lane & 15, quad = lane >> 4;
  const int wm = w & 1, wn = w >> 1;
  const int m0 = blockIdx.x * 128;
  const int n0 = blockIdx.y * 128;
  f32x4 acc[4][4];
  for (int mt = 0; mt < 4; ++mt)
    for (int nt = 0; nt < 4; ++nt) acc[mt][nt] = (f32x4){0.f, 0.f, 0.f, 0.f};

  for (int k0 = 0; k0 < E_; k0 += 32) {
    __syncthreads();
    for (int l = 0; l < 2; ++l) {
      int c = tid + 256 * l;
      int row = c >> 2, k8 = (c & 3) * 8;
      *(bf16x8*)&As[row][k8] = *(const bf16x8*)&Ab[(size_t)(m0 + row) * E_ + k0 + k8];
      *(bf16x8*)&Bs[row][k8] = *(const bf16x8*)&Wb[(size_t)(n0 + row) * E_ + k0 + k8];
    }
    __syncthreads();
    bf16x8 a[4], bfr[4];
    for (int mt = 0; mt < 4; ++mt)
      a[mt] = *(const bf16x8*)&As[wm * 64 + mt * 16 + l15][quad * 8];
    for (int nt = 0; nt < 4; ++nt)
      bfr[nt] = *(const bf16x8*)&Bs[wn * 64 + nt * 16 + l15][quad * 8];
    for (int mt = 0; mt < 4; ++mt)
      for (int nt = 0; nt < 4; ++nt)
        acc[mt][nt] = __builtin_amdgcn_mfma_f32_16x16x32_bf16(a[mt], bfr[nt], acc[mt][nt], 0, 0, 0);
  }
  for (int mt = 0; mt < 4; ++mt)
    for (int nt = 0; nt < 4; ++nt) {
      const int n = n0 + wn * 64 + nt * 16 + l15;
      for (int i = 0; i < 4; ++i) {
        const int m = m0 + wm * 64 + mt * 16 + quad * 4 + i;
        out[(size_t)m * E_ + n] = acc[mt][nt][i];
      }
    }
}

// ---------------------------------------------------------------------------
// Flash attention, MFMA, static-max softmax, SPLIT-K.
// Static max => softmax partials are LINEAR: each (bh, q-pair) is processed
// by TWO blocks (kh=0: kt in [0,mid), kh=1: [mid,qt]), each writing
// unnormalized O partials (bf16) + lsum partials (fp32). merge_kernel
// normalizes. Grid 1024 -> 4 blocks/CU (was 2; 50% dead latency at 2
// waves/SIMD, r9/r10). Uniform ~16.5 tiles/block. XCD swizzle keeps 4 bh
// per XCD and both kh halves of a pair on the same XCD (K/V L2 reuse).
// Masked rows (mask[s]=0) output V[s]: written directly by the kh=0 block.
// ---------------------------------------------------------------------------
__global__ __launch_bounds__(256) void flash_mfma(
    const short* __restrict__ qb, const short* __restrict__ kb,
    const short* __restrict__ vbT, const int* __restrict__ maskp,
    short* __restrict__ pb0, short* __restrict__ pb1,
    float* __restrict__ lb0, float* __restrict__ lb1,
    short* __restrict__ ob) {
  __shared__ __align__(16) short Ks[64][72];
  __shared__ __align__(16) short VT[64][72];
  __shared__ __align__(16) short Pl[4][16][72];
  __shared__ float kbias[64];
  const int tid = threadIdx.x;
  const int w = tid >> 6, lane = tid & 63;
  const int l15 = lane & 15, quad = lane >> 4;
  const int bid = blockIdx.x;
  const int u = bid & 7, v = bid >> 3;       // u -> XCD under id&7 model
  const int bh = (u << 2) | (v & 3);         // 4 bh per XCD
  const int w2 = v >> 2;                     // 0..31
  const int pair = w2 & 15;                  // q-tile pair id
  const int kh = w2 >> 4;                    // split half: 0 or 1
  const int b = bh >> 3, hd = bh & 7;
  const short* qbase = qb + (size_t)bh * S_ * D_;
  const short* kbase = kb + (size_t)bh * S_ * D_;
  const short* vtb   = vbT + (size_t)bh * D_ * S_;
  short* PB = kh ? pb1 : pb0;
  float* LB = kh ? lb1 : lb0;
  const float c2 = 0.1803368801f;            // 0.125 * log2(e)
  bf16x8 ones;
  for (int j = 0; j < 8; ++j) ones[j] = (short)0x3F80;  // bf16 1.0

  for (int seg = 0; seg < 2; ++seg) {
    const int qt = (seg == 0) ? pair : 31 - pair;
    const int r0 = qt * 64;
    const int mid = (qt + 2) >> 1;           // ceil((qt+1)/2)
    const int lo = kh ? mid : 0;
    const int hi = kh ? (qt + 1) : mid;
    bf16x8 aq[2];
    {
      const short* qrow = qbase + (size_t)(r0 + 16 * w + l15) * D_;
      aq[0] = *(const bf16x8*)&qrow[quad * 8];
      aq[1] = *(const bf16x8*)&qrow[32 + quad * 8];
    }
    f32x4 o[4], lsum;
    for (int no = 0; no < 4; ++no) o[no] = (f32x4){0.f, 0.f, 0.f, 0.f};
    lsum = (f32x4){0.f, 0.f, 0.f, 0.f};

    for (int kt = lo; kt < hi; ++kt) {
      const int t0 = kt * 64;
      __syncthreads();                       // prior tile fully consumed
      for (int l = 0; l < 2; ++l) {
        int idx = tid + 256 * l;
        int row = idx >> 3, ch = (idx & 7) * 8;
        *(bf16x8*)&Ks[row][ch] = *(const bf16x8*)(kbase + (size_t)(t0 + row) * D_ + ch);
        *(bf16x8*)&VT[row][ch] = *(const bf16x8*)(vtb + (size_t)row * S_ + t0 + ch);
      }
      if (tid < 64)
        kbias[tid] = maskp[b * S_ + t0 + tid] ? -23.08312f : -1.0e38f;
      __syncthreads();
      f32x4 sfr[4];
      for (int nb = 0; nb < 4; ++nb) sfr[nb] = (f32x4){0.f, 0.f, 0.f, 0.f};
      for (int nb = 0; nb < 4; ++nb)
        for (int ks = 0; ks < 2; ++ks) {
          bf16x8 bk = *(const bf16x8*)&Ks[l15 + 16 * nb][32 * ks + quad * 8];
          sfr[nb] = __builtin_amdgcn_mfma_f32_16x16x32_bf16(aq[ks], bk, sfr[nb], 0, 0, 0);
        }
      if (kt < qt) {                         // interior tiles: no causal test
        for (int nb = 0; nb < 4; ++nb) {
          const float bb = kbias[l15 + 16 * nb];
          for (int i = 0; i < 4; ++i)
            Pl[w][quad * 4 + i][l15 + 16 * nb] = f2bf_fast(exp2f(sfr[nb][i] * c2 + bb));
        }
      } else {                               // boundary tile: add causal mask
        for (int nb = 0; nb < 4; ++nb) {
          const int tg = l15 + 16 * nb;
          const float bb = kbias[l15 + 16 * nb];
          for (int i = 0; i < 4; ++i) {
            const float bbi = (tg > 16 * w + quad * 4 + i) ? -1.0e38f : bb;
            Pl[w][quad * 4 + i][l15 + 16 * nb] = f2bf_fast(exp2f(sfr[nb][i] * c2 + bbi));
          }
        }
      }
      asm volatile("s_waitcnt lgkmcnt(0)" ::: "memory");  // own-wave Pl writes
      bf16x8 ap0 = *(const bf16x8*)&Pl[w][l15][quad * 8];
      bf16x8 ap1 = *(const bf16x8*)&Pl[w][l15][32 + quad * 8];
      for (int no = 0; no < 4; ++no) {
        bf16x8 bv0 = *(const bf16x8*)&VT[16 * no + l15][quad * 8];
        bf16x8 bv1 = *(const bf16x8*)&VT[16 * no + l15][32 + quad * 8];
        o[no] = __builtin_amdgcn_mfma_f32_16x16x32_bf16(ap0, bv0, o[no], 0, 0, 0);
        o[no] = __builtin_amdgcn_mfma_f32_16x16x32_bf16(ap1, bv1, o[no], 0, 0, 0);
      }
      lsum = __builtin_amdgcn_mfma_f32_16x16x32_bf16(ap0, ones, lsum, 0, 0, 0);
      lsum = __builtin_amdgcn_mfma_f32_16x16x32_bf16(ap1, ones, lsum, 0, 0, 0);
    }
    // epilogue: write partials; kh=0 also writes V rows for masked queries
    for (int i = 0; i < 4; ++i) {
      const int s = r0 + 16 * w + quad * 4 + i;
      const int qm = maskp[b * S_ + s];
      const size_t row = (size_t)(b * S_ + s) * E_ + hd * D_;
      if (kh == 0 && !qm) {
        for (int no = 0; no < 4; ++no) {
          const int d = l15 + 16 * no;
          ob[row + d] = vtb[(size_t)d * S_ + s];
        }
      }
      for (int no = 0; no < 4; ++no)
        PB[row + l15 + 16 * no] = f2bf(o[no][i]);
      if (l15 == 0)
        LB[bh * S_ + s] = lsum[i];
    }
  }
}

// ---------------------------------------------------------------------------
// merge: ob[m][e] = (P0 + P1) / (l0 + l1) for unmasked rows (masked rows
// were written by flash kh=0). 8 elems per thread.
// ---------------------------------------------------------------------------
__global__ __launch_bounds__(256) void merge_kernel(
    const short* __restrict__ pb0, const short* __restrict__ pb1,
    const float* __restrict__ lb0, const float* __restrict__ lb1,
    const int* __restrict__ maskp, short* __restrict__ ob) {
  int idx = blockIdx.x * 256 + threadIdx.x;  // 8192*64 threads
  int m = idx >> 6, e = (idx & 63) * 8;
  if (!maskp[m]) return;                     // masked row: flash wrote V
  int b = m >> 11, s = m & (S_ - 1);
  int bh = b * 8 + (e >> 6);
  float l = lb0[bh * S_ + s] + lb1[bh * S_ + s];
  float inv = 1.f / l;
  bf16x8 p0 = *(const bf16x8*)&pb0[(size_t)m * E_ + e];
  bf16x8 p1 = *(const bf16x8*)&pb1[(size_t)m * E_ + e];
  bf16x8 r;
  for (int j = 0; j < 8; ++j)
    r[j] = f2bf((bf2f(p0[j]) + bf2f(p1[j])) * inv);
  *(bf16x8*)&ob[(size_t)m * E_ + e] = r;
}

extern "C" void kernel_launch(void* const* d_in, const int* in_sizes, int n_in,
                              void* d_out, int out_size, void* d_ws, size_t ws_size,
                              hipStream_t stream) {
  const float* x    = (const float*)d_in[0];
  const int*   mask = (const int*)d_in[1];
  const float* Win  = (const float*)d_in[2];
  const float* Wout = (const float*)d_in[3];
  float* out = (float*)d_out;

  short* Xb    = (short*)d_ws;               // 8192*512
  short* Winb  = Xb + 8192 * 512;            // 1536*512
  short* Woutb = Winb + 1536 * 512;          // 512*512
  short* qb    = Woutb + 512 * 512;          // 32*2048*64 each
  short* kb    = qb + 32 * 2048 * 64;
  short* vbT   = kb + 32 * 2048 * 64;        // [bh][d][s] transposed
  short* ob    = vbT + 32 * 2048 * 64;       // 8192*512
  short* pb0   = ob + 8192 * 512;            // partial O, half 0 (bf16)
  short* pb1   = pb0 + 8192 * 512;           // partial O, half 1
  float* lb0   = (float*)(pb1 + 8192 * 512); // lsum partials [32][2048]
  float* lb1   = lb0 + 32 * 2048;            // total ws ~61.3 MB

  cvt_bf16<<<4096, 256, 0, stream>>>(x, Xb, 8192 * 512 / 4);
  cvt_bf16<<<768, 256, 0, stream>>>(Win, Winb, 1536 * 512 / 4);
  cvt_bf16<<<256, 256, 0, stream>>>(Wout, Woutb, 512 * 512 / 4);
  gemm_qkv_mfma<<<dim3(64, 12), 256, 0, stream>>>(Xb, Winb, qb, kb, vbT);
  flash_mfma<<<1024, 256, 0, stream>>>(qb, kb, vbT, mask, pb0, pb1, lb0, lb1, ob);
  merge_kernel<<<2048, 256, 0, stream>>>(pb0, pb1, lb0, lb1, mask, ob);
  gemm_out_mfma<<<dim3(64, 4), 256, 0, stream>>>(ob, Woutb, out);
}